// Round 3
// baseline (507.402 us; speedup 1.0000x reference)
//
#include <hip/hip_runtime.h>
#include <hip/hip_bf16.h>
#include <math.h>

#define B_SZ   32
#define NXX    16384
#define IN_DIM 3
#define DIM    64
#define JM     16
#define MODE   128
#define RANKK  4
#define FC_DIM 128
#define N_LAY  3

typedef __attribute__((ext_vector_type(8))) short bf16x8;
typedef __attribute__((ext_vector_type(4))) float f32x4;
typedef unsigned short u16;

// Fast gelu: v * sigmoid(2u), u = sqrt(2/pi)*(v + 0.044715 v^3).
__device__ __forceinline__ float gelu_fast(float v) {
    float p = v * (0.7978845608f + 0.0356774081f * v * v);
    float e = __expf(-2.f * p);
    return v * __builtin_amdgcn_rcpf(1.f + e);
}
__device__ __forceinline__ u16 to_bf16(float v) {
    __hip_bfloat16 b = __float2bfloat16(v);
    return *(u16*)&b;
}

// ---------------------------------------------------------------------------
__global__ __launch_bounds__(256) void k_zero(float* __restrict__ p, int n) {
    int i = blockIdx.x * 256 + threadIdx.x;
    if (i < n) p[i] = 0.f;
}

// H[j,k,l] bf16 row-major (l contig = A-frag-ready for m=k, kk=l).
__global__ __launch_bounds__(256) void k_build_H(
        const float* __restrict__ Dout, const float* __restrict__ Din,
        const float* __restrict__ product, const float* __restrict__ A,
        const float* __restrict__ Bm, u16* __restrict__ Hbf) {
    int idx = blockIdx.x * 256 + threadIdx.x;
    int j = idx >> 14;
    int k = (idx >> 7) & 127;
    int l = idx & 127;
    float v = Dout[j * MODE + k] * Din[j * MODE + l] * product[k * MODE + l];
#pragma unroll
    for (int r = 0; r < RANKK; ++r)
        v += A[(j * RANKK + r) * MODE + k] * Bm[(j * RANKK + r) * MODE + l];
    Hbf[idx] = to_bf16(v);
}

// WsT[lay][j][o][i] = Wsp[lay][i][o][j] bf16 (i contig).  grid 768 x 256.
__global__ __launch_bounds__(256) void k_setup_wst(
        const float* __restrict__ Wsp, u16* __restrict__ WsT) {
    int idx = blockIdx.x * 256 + threadIdx.x;   // ((lay*16+j)*64+o)*64+i
    int i = idx & 63, o = (idx >> 6) & 63, j = (idx >> 12) & 15, lay = idx >> 16;
    WsT[idx] = to_bf16(Wsp[(((size_t)lay * 64 + i) * 64 + o) * 16 + j]);
}

// bases (fp32 [x][k]) -> FRAG-MAJOR single bf16 plane.  grid 8192 x 256.
__global__ __launch_bounds__(256) void k_setup_bases(
        const float* __restrict__ bases, u16* __restrict__ bh) {
    int idx = blockIdx.x * 256 + threadIdx.x;
    int x = idx >> 7, k = idx & 127;
    size_t off = (size_t)(k >> 3) * 131072 + (size_t)x * 8 + (k & 7);
    bh[off] = to_bf16(bases[idx]);
}

// wbT[l][x] = wbases[x][l], single bf16 plane.  grid (512, 4) x 256, LDS-tiled.
__global__ __launch_bounds__(256) void k_setup_wbT(
        const float* __restrict__ wb, u16* __restrict__ Th) {
    __shared__ float tile[32][33];
    int bx = blockIdx.x, bl = blockIdx.y;
    int t = threadIdx.x;
    int i = t >> 5, jj = t & 31;
#pragma unroll
    for (int r = 0; r < 4; ++r)
        tile[i + r * 8][jj] = wb[(size_t)(bx * 32 + i + r * 8) * MODE + bl * 32 + jj];
    __syncthreads();
#pragma unroll
    for (int r = 0; r < 4; ++r) {
        int l = bl * 32 + i + r * 8;
        int x = bx * 32 + jj;
        Th[(size_t)l * NXX + x] = to_bf16(tile[jj][i + r * 8]);
    }
}

// W1T[f*64+c] = W1[c*128+f] single bf16 plane.  grid 32 x 256
__global__ __launch_bounds__(256) void k_setup_w1t(
        const float* __restrict__ W1, u16* __restrict__ wh) {
    int i = blockIdx.x * 256 + threadIdx.x;
    int f = i >> 6, c = i & 63;
    wh[i] = to_bf16(W1[c * FC_DIM + f]);
}

// fc0: h[b,x,c] (single bf16 plane), coalesced ushort8 stores.
// grid (512, 32) x 256.
__global__ __launch_bounds__(256) void k_fc0(
        const float* __restrict__ x, const float* __restrict__ W0,
        const float* __restrict__ b0, u16* __restrict__ hh) {
    __shared__ float w0s[IN_DIM * DIM + DIM];
    int t = threadIdx.x;
    if (t < IN_DIM * DIM) w0s[t] = W0[t];
    if (t < DIM) w0s[IN_DIM * DIM + t] = b0[t];
    __syncthreads();
    int b = blockIdx.y;
    int xi = blockIdx.x * 32 + (t >> 3);
    int c8 = (t & 7) * 8;
    const float* xp = x + ((size_t)b * NXX + xi) * IN_DIM;
    float x0 = xp[0], x1 = xp[1], x2 = xp[2];
    u16 rh[8];
#pragma unroll
    for (int i = 0; i < 8; ++i) {
        int c = c8 + i;
        float v = x0 * w0s[c] + x1 * w0s[DIM + c] + x2 * w0s[2 * DIM + c]
                + w0s[3 * DIM + c];
        rh[i] = to_bf16(v);
    }
    size_t o = ((size_t)(b << 14) + xi) * 64 + c8;
    *(ushort4*)(hh + o)     = make_ushort4(rh[0], rh[1], rh[2], rh[3]);
    *(ushort4*)(hh + o + 4) = make_ushort4(rh[4], rh[5], rh[6], rh[7]);
}

// ---------------------------------------------------------------------------
// Spectral via MFMA: xh[b][c][l] += sum_x h[b][x][c] * wbases[x][l]
// grid (32 b, 32 ks) x 256 (4 waves; wave = 16c x 32l), 512-x slab per block.
#define SPAD 72
__global__ __launch_bounds__(256) void k_spectral_mfma(
        const u16* __restrict__ Hh,
        const u16* __restrict__ Wh,
        float* __restrict__ xh) {
    __shared__ u16 Ash[64 * SPAD];
    int t = threadIdx.x;
    int wave = t >> 6, lane = t & 63, quad = lane >> 4, l16 = lane & 15;
    int b = blockIdx.x;
    int x0 = blockIdx.y * 512;
    int cq = (t & 15) * 4;
    int xq = (t >> 4) * 4;
    int colw = (xq + ((t & 7) << 3)) & 63;
    const u16* srch = Hh + ((size_t)(b << 14) + x0 + xq) * 64 + cq;
    int l0 = wave * 32;
    const u16* w0h = Wh + (size_t)(l0 + l16) * NXX + x0;
    const u16* w1h = Wh + (size_t)(l0 + 16 + l16) * NXX + x0;
    f32x4 acc[4][2] = {};
    for (int kt = 0; kt < 512; kt += 64) {
        __syncthreads();
        {
            const u16* s = srch + (size_t)kt * 64;
            ushort4 r0 = *(const ushort4*)(s);
            ushort4 r1 = *(const ushort4*)(s + 64);
            ushort4 r2 = *(const ushort4*)(s + 128);
            ushort4 r3 = *(const ushort4*)(s + 192);
            *(ushort4*)&Ash[(cq + 0) * SPAD + colw] = make_ushort4(r0.x, r1.x, r2.x, r3.x);
            *(ushort4*)&Ash[(cq + 1) * SPAD + colw] = make_ushort4(r0.y, r1.y, r2.y, r3.y);
            *(ushort4*)&Ash[(cq + 2) * SPAD + colw] = make_ushort4(r0.z, r1.z, r2.z, r3.z);
            *(ushort4*)&Ash[(cq + 3) * SPAD + colw] = make_ushort4(r0.w, r1.w, r2.w, r3.w);
        }
        __syncthreads();
#pragma unroll
        for (int k0 = 0; k0 < 64; k0 += 32) {
            bf16x8 afh[4];
#pragma unroll
            for (int ct = 0; ct < 4; ++ct) {
                int rr = ct * 16 + l16;
                int ro = rr * SPAD + (((k0 + quad * 8) + (((rr >> 2) & 7) << 3)) & 63);
                afh[ct] = *(const bf16x8*)&Ash[ro];
            }
            int go = kt + k0 + quad * 8;
            bf16x8 b0h = *(const bf16x8*)(w0h + go);
            bf16x8 b1h = *(const bf16x8*)(w1h + go);
#pragma unroll
            for (int ct = 0; ct < 4; ++ct) {
                acc[ct][0] = __builtin_amdgcn_mfma_f32_16x16x32_bf16(afh[ct], b0h, acc[ct][0], 0, 0, 0);
                acc[ct][1] = __builtin_amdgcn_mfma_f32_16x16x32_bf16(afh[ct], b1h, acc[ct][1], 0, 0, 0);
            }
        }
    }
    float* xb = xh + (size_t)(b << 6) * 128;
#pragma unroll
    for (int ct = 0; ct < 4; ++ct)
#pragma unroll
        for (int lt = 0; lt < 2; ++lt)
#pragma unroll
            for (int r = 0; r < 4; ++r)
                atomicAdd(xb + (size_t)(ct * 16 + quad * 4 + r) * 128 + l0 + lt * 16 + l16,
                          acc[ct][lt][r]);
}

// ---------------------------------------------------------------------------
// hmix2: one block per b.  j-loop with in-register y accumulation; Ts is
// wave-private (each wave owns 32 k rows) -> NO barriers in the loop; NO
// atomics.  Epilogue writes Abuf (y|Wconv) bf16 frag-major directly
// (replaces k_build_A + ybuf + its zeroing).
#define XPAD 136
#define TPAD 72
__global__ __launch_bounds__(256) void k_hmix2(
        const float* __restrict__ xh, const u16* __restrict__ Hbf,
        const u16* __restrict__ WsT, const float* __restrict__ Wconv,
        u16* __restrict__ Ah, int lay) {
    __shared__ u16 xsb[64 * XPAD];   // [i][l]
    __shared__ u16 Ts[128 * TPAD];   // [k][i], rows wave-private
    int t = threadIdx.x;
    int wave = t >> 6, lane = t & 63, quad = lane >> 4, l16 = lane & 15;
    int b = blockIdx.x;
    const float* xb = xh + (size_t)b * DIM * MODE;
    for (int idx = t; idx < DIM * MODE; idx += 256)
        xsb[(idx >> 7) * XPAD + (idx & 127)] = to_bf16(xb[idx]);
    // Wconv region of Abuf (ks 4,5) while staging settles
    for (int idx = 8192 + t; idx < 12288; idx += 256) {
        int i = idx & 7, ll = (idx >> 3) & 15, qq = (idx >> 7) & 3,
            ot = (idx >> 9) & 3, ks = idx >> 11;
        int o = ot * 16 + ll;
        int k = ks * 32 + qq * 8 + i;
        Ah[(size_t)b * 12288 + idx] =
            to_bf16(Wconv[(size_t)lay * DIM * DIM + o * DIM + (k - 128)]);
    }
    __syncthreads();
    int k_base = wave * 32;
    f32x4 accy[4][2] = {};   // y[o][k] accumulated over j
    for (int j = 0; j < JM; ++j) {
        // phase 1: T[k][i] = sum_l H[j][k][l] * xh[b][i][l]
        {
            f32x4 acc[2][4] = {};
            const u16* Hj = Hbf + (size_t)j * MODE * MODE;
#pragma unroll
            for (int l0 = 0; l0 < 128; l0 += 32) {
                bf16x8 af[2], bf[4];
#pragma unroll
                for (int mt = 0; mt < 2; ++mt)
                    af[mt] = *(const bf16x8*)(Hj + (size_t)(k_base + mt * 16 + l16) * 128 + l0 + quad * 8);
#pragma unroll
                for (int nt = 0; nt < 4; ++nt)
                    bf[nt] = *(const bf16x8*)&xsb[(nt * 16 + l16) * XPAD + l0 + quad * 8];
#pragma unroll
                for (int mt = 0; mt < 2; ++mt)
#pragma unroll
                    for (int nt = 0; nt < 4; ++nt)
                        acc[mt][nt] = __builtin_amdgcn_mfma_f32_16x16x32_bf16(af[mt], bf[nt], acc[mt][nt], 0, 0, 0);
            }
#pragma unroll
            for (int mt = 0; mt < 2; ++mt)
#pragma unroll
                for (int nt = 0; nt < 4; ++nt)
#pragma unroll
                    for (int r = 0; r < 4; ++r)
                        Ts[(k_base + mt * 16 + quad * 4 + r) * TPAD + nt * 16 + l16] =
                            to_bf16(acc[mt][nt][r]);
        }
        // phase 2: y[o][k] += sum_i WsT[j][o][i] * T[k][i]  (same-wave Ts rows)
        {
            const u16* Wj = WsT + ((size_t)lay * JM + j) * DIM * DIM;
#pragma unroll
            for (int i0 = 0; i0 < 64; i0 += 32) {
                bf16x8 af[4], bf[2];
#pragma unroll
                for (int mt = 0; mt < 4; ++mt)
                    af[mt] = *(const bf16x8*)(Wj + (size_t)(mt * 16 + l16) * 64 + i0 + quad * 8);
#pragma unroll
                for (int nt = 0; nt < 2; ++nt)
                    bf[nt] = *(const bf16x8*)&Ts[(k_base + nt * 16 + l16) * TPAD + i0 + quad * 8];
#pragma unroll
                for (int mt = 0; mt < 4; ++mt)
#pragma unroll
                    for (int nt = 0; nt < 2; ++nt)
                        accy[mt][nt] = __builtin_amdgcn_mfma_f32_16x16x32_bf16(af[mt], bf[nt], accy[mt][nt], 0, 0, 0);
            }
        }
    }
    // epilogue: y -> Abuf frag-major bf16.
    // o = mt*16 + quad*4 + r ; k = wave*32 + nt*16 + l16
    // frag idx = (((wave*4+mt)*4 + nt*2 + (l16>>3))*16 + quad*4 + r)*8 + (l16&7)
#pragma unroll
    for (int mt = 0; mt < 4; ++mt)
#pragma unroll
        for (int nt = 0; nt < 2; ++nt)
#pragma unroll
            for (int r = 0; r < 4; ++r) {
                int idx = (((wave * 4 + mt) * 4 + nt * 2 + (l16 >> 3)) * 16
                           + quad * 4 + r) * 8 + (l16 & 7);
                Ah[(size_t)b * 12288 + idx] = to_bf16(accy[mt][nt][r]);
            }
}

// ---------------------------------------------------------------------------
// inv_conv: h' = act(A(64x192) @ B(192 x 16384x) + bconv), in-place on h.
// 2 x-tiles (128 each) per block, grid 2048.  A staged to LDS once; B-frags
// (bases from frag-major plane, h direct from global — both L2-resident)
// live in registers; tile-1 fragments are prefetched before tile-0's
// epilogue so their latency hides under gelu/pack/store.  osh (16KB) used
// only for dense output stores.  LDS 40KB -> 4 blocks/CU.
template <bool DO_MLP>
__global__ __launch_bounds__(256, 4) void k_inv_conv_mfma(
        const u16* __restrict__ Afh,
        const u16* __restrict__ Bfh,
        u16* __restrict__ Hh,
        const float* __restrict__ bconv, int lay,
        const u16* __restrict__ W1h,
        const float* __restrict__ b1, const float* __restrict__ W2,
        const float* __restrict__ b2, float* __restrict__ out) {
    __shared__ u16 Ash[12288];       // A fragments, frag-major (24KB)
    __shared__ u16 osh[128 * 64];    // output staging, XOR-swizzled (16KB)
    int t = threadIdx.x;
    int wave = t >> 6, lane = t & 63, quad = lane >> 4, l16 = lane & 15;
    // XCD-bijective swizzle: 2048 blocks = 8 XCD x 256; each XCD owns all
    // 32 b x 8 x-tiles (2048 consecutive x) -> bases slab L2-resident.
    int bid = blockIdx.x;
    int swz = (bid & 7) * 256 + (bid >> 3);
    int b = swz & 31;
    int x0 = (swz >> 5) * 256;       // 2 sub-tiles: x0, x0+128
    int xw = wave * 32;

    // stage A (24KB) once per block
    const u16* afb = Afh + (size_t)b * 12288;
#pragma unroll
    for (int i = 0; i < 6; ++i) {
        int idx = i * 256 + t;
        *(bf16x8*)&Ash[idx * 8] = *(const bf16x8*)(afb + (size_t)idx * 8);
    }

    auto loadB = [&](int x0t, bf16x8 (&bg)[4][2], bf16x8 (&hf)[2][2]) {
#pragma unroll
        for (int ks = 0; ks < 4; ++ks)
#pragma unroll
            for (int x2 = 0; x2 < 2; ++x2) {
                int xl = xw + x2 * 16 + l16;
                bg[ks][x2] = *(const bf16x8*)(Bfh + (size_t)((ks * 4 + quad) * 16384 + x0t + xl) * 8);
            }
#pragma unroll
        for (int ks = 0; ks < 2; ++ks)
#pragma unroll
            for (int x2 = 0; x2 < 2; ++x2) {
                int xl = xw + x2 * 16 + l16;
                hf[ks][x2] = *(const bf16x8*)(Hh + ((size_t)(b << 14) + x0t + xl) * 64
                                              + ks * 32 + quad * 8);
            }
    };

    auto ksloop = [&](const bf16x8 (&bg)[4][2], const bf16x8 (&hf)[2][2],
                      f32x4 (&acc)[4][2]) {
#pragma unroll
        for (int ks = 0; ks < 6; ++ks) {
            bf16x8 afh[4];
#pragma unroll
            for (int ot = 0; ot < 4; ++ot)
                afh[ot] = *(const bf16x8*)&Ash[(((ks * 4 + ot) * 4 + quad) * 16 + l16) * 8];
#pragma unroll
            for (int ot = 0; ot < 4; ++ot)
#pragma unroll
                for (int x2 = 0; x2 < 2; ++x2)
                    acc[ot][x2] = __builtin_amdgcn_mfma_f32_16x16x32_bf16(
                        afh[ot], ks < 4 ? bg[ks][x2] : hf[ks - 4][x2],
                        acc[ot][x2], 0, 0, 0);
        }
    };

    // lay 0/1 epilogue: gelu -> osh (own rows) -> barrier -> dense store
    auto epi_store = [&](int x0t, f32x4 (&acc)[4][2], bool lastTile) {
#pragma unroll
        for (int ot = 0; ot < 4; ++ot) {
            float4 bc = *(const float4*)(bconv + lay * DIM + ot * 16 + quad * 4);
#pragma unroll
            for (int x2 = 0; x2 < 2; ++x2) {
                int xl = xw + x2 * 16 + l16;
                ushort4 uh;
                uh.x = to_bf16(gelu_fast(acc[ot][x2][0] + bc.x));
                uh.y = to_bf16(gelu_fast(acc[ot][x2][1] + bc.y));
                uh.z = to_bf16(gelu_fast(acc[ot][x2][2] + bc.z));
                uh.w = to_bf16(gelu_fast(acc[ot][x2][3] + bc.w));
                int col = ot * 16 + quad * 4;
                *(ushort4*)&osh[xl * 64 + (col ^ ((xl & 7) << 3))] = uh;
            }
        }
        __syncthreads();
#pragma unroll
        for (int it = 0; it < 4; ++it) {
            int idx = it * 256 + t;
            int row = idx >> 3, c8 = (idx & 7) * 8;
            size_t dst = ((size_t)(b << 14) + x0t + row) * 64 + c8;
            *(bf16x8*)(Hh + dst) =
                *(const bf16x8*)&osh[row * 64 + (c8 ^ ((row & 7) << 3))];
        }
        if (!lastTile) __syncthreads();
    };

    // lay 2 epilogue: fused MLP.  osh rows are wave-private -> no barriers.
    auto epi_mlp = [&](int x0t, f32x4 (&acc)[4][2]) {
#pragma unroll
        for (int ot = 0; ot < 4; ++ot) {
            float4 bc = *(const float4*)(bconv + lay * DIM + ot * 16 + quad * 4);
#pragma unroll
            for (int x2 = 0; x2 < 2; ++x2) {
                int xl = xw + x2 * 16 + l16;
                ushort4 uh;
                uh.x = to_bf16(acc[ot][x2][0] + bc.x);
                uh.y = to_bf16(acc[ot][x2][1] + bc.y);
                uh.z = to_bf16(acc[ot][x2][2] + bc.z);
                uh.w = to_bf16(acc[ot][x2][3] + bc.w);
                int col = ot * 16 + quad * 4;
                *(ushort4*)&osh[xl * 64 + (col ^ ((xl & 7) << 3))] = uh;
            }
        }
#pragma unroll
        for (int x2 = 0; x2 < 2; ++x2) {
            int xl = xw + x2 * 16 + l16;
            bf16x8 ah[2];
#pragma unroll
            for (int ks = 0; ks < 2; ++ks) {
                int ko = ks * 32 + quad * 8;
                ah[ks] = *(const bf16x8*)&osh[xl * 64 + (ko ^ ((xl & 7) << 3))];
            }
            float vo[4] = {0.f, 0.f, 0.f, 0.f};
#pragma unroll
            for (int ft = 0; ft < 8; ++ft) {
                f32x4 a2 = {};
#pragma unroll
                for (int ks = 0; ks < 2; ++ks) {
                    size_t o = (size_t)(ft * 16 + l16) * 64 + ks * 32 + quad * 8;
                    bf16x8 bh = *(const bf16x8*)(W1h + o);
                    a2 = __builtin_amdgcn_mfma_f32_16x16x32_bf16(ah[ks], bh, a2, 0, 0, 0);
                }
                float bb = b1[ft * 16 + l16];
                float w2 = W2[ft * 16 + l16];
#pragma unroll
                for (int r = 0; r < 4; ++r)
                    vo[r] += gelu_fast(a2[r] + bb) * w2;
            }
#pragma unroll
            for (int r = 0; r < 4; ++r) {
                float v = vo[r];
                v += __shfl_xor(v, 1);
                v += __shfl_xor(v, 2);
                v += __shfl_xor(v, 4);
                v += __shfl_xor(v, 8);
                vo[r] = v;
            }
            if (l16 == 0) {
                float bb2 = b2[0];
                float4 o4 = make_float4(vo[0] + bb2, vo[1] + bb2,
                                        vo[2] + bb2, vo[3] + bb2);
                *(float4*)(out + (size_t)b * NXX + x0t + xw + x2 * 16 + quad * 4) = o4;
            }
        }
    };

    // ---- tile 0 ----
    bf16x8 bgA[4][2], hfA[2][2];
    loadB(x0, bgA, hfA);
    __syncthreads();                 // Ash ready
    f32x4 acc[4][2] = {};
    ksloop(bgA, hfA, acc);
    // prefetch tile 1 operands; latency hides under tile-0 epilogue/store
    bf16x8 bgB[4][2], hfB[2][2];
    loadB(x0 + 128, bgB, hfB);
    if (!DO_MLP) epi_store(x0, acc, false);
    else         epi_mlp(x0, acc);
    // ---- tile 1 ----
    f32x4 acc2[4][2] = {};
    ksloop(bgB, hfB, acc2);
    if (!DO_MLP) epi_store(x0 + 128, acc2, true);
    else         epi_mlp(x0 + 128, acc2);
}

// ---------------------------------------------------------------------------
extern "C" void kernel_launch(void* const* d_in, const int* in_sizes, int n_in,
                              void* d_out, int out_size, void* d_ws, size_t ws_size,
                              hipStream_t stream) {
    const float* x      = (const float*)d_in[0];
    const float* bases  = (const float*)d_in[1];
    const float* wbases = (const float*)d_in[2];
    const float* product= (const float*)d_in[3];
    const float* Dout   = (const float*)d_in[4];
    const float* Din    = (const float*)d_in[5];
    const float* A      = (const float*)d_in[6];
    const float* Bm     = (const float*)d_in[7];
    const float* Wsp    = (const float*)d_in[8];
    const float* Wconv  = (const float*)d_in[9];
    const float* bconv  = (const float*)d_in[10];
    const float* W0     = (const float*)d_in[11];
    const float* b0     = (const float*)d_in[12];
    const float* W1     = (const float*)d_in[13];
    const float* b1     = (const float*)d_in[14];
    const float* W2     = (const float*)d_in[15];
    const float* b2     = (const float*)d_in[16];
    float* out = (float*)d_out;

    const size_t need = 79314944;
    if (ws_size < need) {
        k_zero<<<dim3((out_size + 255) / 256), dim3(256), 0, stream>>>(out, out_size);
        return;
    }

    char* W = (char*)d_ws;
    size_t off = 0;
    auto alloc = [&](size_t bytes) { void* p = W + off; off += bytes; return p; };
    u16*   Hbf      = (u16*)alloc(524288);
    u16*   WsT      = (u16*)alloc(393216);
    u16*   bases_hi = (u16*)alloc(4194304);
    u16*   wbT_hi   = (u16*)alloc(4194304);
    u16*   Abuf_hi  = (u16*)alloc(786432);
    float* ybuf     = (float*)alloc(1048576);   // unused (kept for layout)
    float* xh       = (float*)alloc(1048576);
    u16*   h_hi     = (u16*)alloc(67108864);
    u16*   w1t_hi   = (u16*)alloc(16384);
    (void)ybuf;

    k_build_H<<<dim3(1024), dim3(256), 0, stream>>>(Dout, Din, product, A, Bm, Hbf);
    k_setup_wst<<<dim3(768), dim3(256), 0, stream>>>(Wsp, WsT);
    k_setup_bases<<<dim3(8192), dim3(256), 0, stream>>>(bases, bases_hi);
    k_setup_wbT<<<dim3(512, 4), dim3(256), 0, stream>>>(wbases, wbT_hi);
    k_setup_w1t<<<dim3(32), dim3(256), 0, stream>>>(W1, w1t_hi);
    k_fc0<<<dim3(512, B_SZ), dim3(256), 0, stream>>>(x, W0, b0, h_hi);

    for (int lay = 0; lay < N_LAY; ++lay) {
        int last = (lay == N_LAY - 1);
        k_zero<<<dim3(1024), dim3(256), 0, stream>>>(xh, 262144);
        k_spectral_mfma<<<dim3(B_SZ, 32), dim3(256), 0, stream>>>(
            h_hi, wbT_hi, xh);
        k_hmix2<<<dim3(B_SZ), dim3(256), 0, stream>>>(
            xh, Hbf, WsT, Wconv, Abuf_hi, lay);
        dim3 g(2048), blk(256);
        if (last)
            k_inv_conv_mfma<true><<<g, blk, 0, stream>>>(
                Abuf_hi, bases_hi, h_hi, bconv, lay,
                w1t_hi, b1, W2, b2, out);
        else
            k_inv_conv_mfma<false><<<g, blk, 0, stream>>>(
                Abuf_hi, bases_hi, h_hi, bconv, lay,
                w1t_hi, b1, W2, b2, out);
    }
}

// Round 4
// 472.133 us; speedup vs baseline: 1.0747x; 1.0747x over previous
//
#include <hip/hip_runtime.h>
#include <hip/hip_bf16.h>
#include <math.h>

#define B_SZ   32
#define NXX    16384
#define IN_DIM 3
#define DIM    64
#define JM     16
#define MODE   128
#define RANKK  4
#define FC_DIM 128
#define N_LAY  3

typedef __attribute__((ext_vector_type(8))) short bf16x8;
typedef __attribute__((ext_vector_type(4))) float f32x4;
typedef unsigned short u16;

// Fast gelu: v * sigmoid(2u), u = sqrt(2/pi)*(v + 0.044715 v^3).
__device__ __forceinline__ float gelu_fast(float v) {
    float p = v * (0.7978845608f + 0.0356774081f * v * v);
    float e = __expf(-2.f * p);
    return v * __builtin_amdgcn_rcpf(1.f + e);
}
__device__ __forceinline__ u16 to_bf16(float v) {
    __hip_bfloat16 b = __float2bfloat16(v);
    return *(u16*)&b;
}

// ---------------------------------------------------------------------------
__global__ __launch_bounds__(256) void k_zero(float* __restrict__ p, int n) {
    int i = blockIdx.x * 256 + threadIdx.x;
    if (i < n) p[i] = 0.f;
}

// H[j,k,l] bf16 row-major (l contig = A-frag-ready for m=k, kk=l).
__global__ __launch_bounds__(256) void k_build_H(
        const float* __restrict__ Dout, const float* __restrict__ Din,
        const float* __restrict__ product, const float* __restrict__ A,
        const float* __restrict__ Bm, u16* __restrict__ Hbf) {
    int idx = blockIdx.x * 256 + threadIdx.x;
    int j = idx >> 14;
    int k = (idx >> 7) & 127;
    int l = idx & 127;
    float v = Dout[j * MODE + k] * Din[j * MODE + l] * product[k * MODE + l];
#pragma unroll
    for (int r = 0; r < RANKK; ++r)
        v += A[(j * RANKK + r) * MODE + k] * Bm[(j * RANKK + r) * MODE + l];
    Hbf[idx] = to_bf16(v);
}

// WsT[lay][j][o][i] = Wsp[lay][i][o][j] bf16 (i contig).  grid 768 x 256.
__global__ __launch_bounds__(256) void k_setup_wst(
        const float* __restrict__ Wsp, u16* __restrict__ WsT) {
    int idx = blockIdx.x * 256 + threadIdx.x;   // ((lay*16+j)*64+o)*64+i
    int i = idx & 63, o = (idx >> 6) & 63, j = (idx >> 12) & 15, lay = idx >> 16;
    WsT[idx] = to_bf16(Wsp[(((size_t)lay * 64 + i) * 64 + o) * 16 + j]);
}

// bases (fp32 [x][k]) -> FRAG-MAJOR single bf16 plane.  grid 8192 x 256.
__global__ __launch_bounds__(256) void k_setup_bases(
        const float* __restrict__ bases, u16* __restrict__ bh) {
    int idx = blockIdx.x * 256 + threadIdx.x;
    int x = idx >> 7, k = idx & 127;
    size_t off = (size_t)(k >> 3) * 131072 + (size_t)x * 8 + (k & 7);
    bh[off] = to_bf16(bases[idx]);
}

// wbT[l][x] = wbases[x][l], single bf16 plane.  grid (512, 4) x 256, LDS-tiled.
__global__ __launch_bounds__(256) void k_setup_wbT(
        const float* __restrict__ wb, u16* __restrict__ Th) {
    __shared__ float tile[32][33];
    int bx = blockIdx.x, bl = blockIdx.y;
    int t = threadIdx.x;
    int i = t >> 5, jj = t & 31;
#pragma unroll
    for (int r = 0; r < 4; ++r)
        tile[i + r * 8][jj] = wb[(size_t)(bx * 32 + i + r * 8) * MODE + bl * 32 + jj];
    __syncthreads();
#pragma unroll
    for (int r = 0; r < 4; ++r) {
        int l = bl * 32 + i + r * 8;
        int x = bx * 32 + jj;
        Th[(size_t)l * NXX + x] = to_bf16(tile[jj][i + r * 8]);
    }
}

// W1T[f*64+c] = W1[c*128+f] single bf16 plane.  grid 32 x 256
__global__ __launch_bounds__(256) void k_setup_w1t(
        const float* __restrict__ W1, u16* __restrict__ wh) {
    int i = blockIdx.x * 256 + threadIdx.x;
    int f = i >> 6, c = i & 63;
    wh[i] = to_bf16(W1[c * FC_DIM + f]);
}

// fc0: h[b,x,c] (single bf16 plane), coalesced ushort8 stores.
// grid (512, 32) x 256.
__global__ __launch_bounds__(256) void k_fc0(
        const float* __restrict__ x, const float* __restrict__ W0,
        const float* __restrict__ b0, u16* __restrict__ hh) {
    __shared__ float w0s[IN_DIM * DIM + DIM];
    int t = threadIdx.x;
    if (t < IN_DIM * DIM) w0s[t] = W0[t];
    if (t < DIM) w0s[IN_DIM * DIM + t] = b0[t];
    __syncthreads();
    int b = blockIdx.y;
    int xi = blockIdx.x * 32 + (t >> 3);
    int c8 = (t & 7) * 8;
    const float* xp = x + ((size_t)b * NXX + xi) * IN_DIM;
    float x0 = xp[0], x1 = xp[1], x2 = xp[2];
    u16 rh[8];
#pragma unroll
    for (int i = 0; i < 8; ++i) {
        int c = c8 + i;
        float v = x0 * w0s[c] + x1 * w0s[DIM + c] + x2 * w0s[2 * DIM + c]
                + w0s[3 * DIM + c];
        rh[i] = to_bf16(v);
    }
    size_t o = ((size_t)(b << 14) + xi) * 64 + c8;
    *(ushort4*)(hh + o)     = make_ushort4(rh[0], rh[1], rh[2], rh[3]);
    *(ushort4*)(hh + o + 4) = make_ushort4(rh[4], rh[5], rh[6], rh[7]);
}

// ---------------------------------------------------------------------------
// Spectral via MFMA: xh[b][c][l] += sum_x h[b][x][c] * wbases[x][l]
// grid (32 b, 32 ks) x 256 (4 waves; wave = 16c x 32l), 512-x slab per block.
#define SPAD 72
__global__ __launch_bounds__(256) void k_spectral_mfma(
        const u16* __restrict__ Hh,
        const u16* __restrict__ Wh,
        float* __restrict__ xh) {
    __shared__ u16 Ash[64 * SPAD];
    int t = threadIdx.x;
    int wave = t >> 6, lane = t & 63, quad = lane >> 4, l16 = lane & 15;
    int b = blockIdx.x;
    int x0 = blockIdx.y * 512;
    int cq = (t & 15) * 4;
    int xq = (t >> 4) * 4;
    int colw = (xq + ((t & 7) << 3)) & 63;
    const u16* srch = Hh + ((size_t)(b << 14) + x0 + xq) * 64 + cq;
    int l0 = wave * 32;
    const u16* w0h = Wh + (size_t)(l0 + l16) * NXX + x0;
    const u16* w1h = Wh + (size_t)(l0 + 16 + l16) * NXX + x0;
    f32x4 acc[4][2] = {};
    for (int kt = 0; kt < 512; kt += 64) {
        __syncthreads();
        {
            const u16* s = srch + (size_t)kt * 64;
            ushort4 r0 = *(const ushort4*)(s);
            ushort4 r1 = *(const ushort4*)(s + 64);
            ushort4 r2 = *(const ushort4*)(s + 128);
            ushort4 r3 = *(const ushort4*)(s + 192);
            *(ushort4*)&Ash[(cq + 0) * SPAD + colw] = make_ushort4(r0.x, r1.x, r2.x, r3.x);
            *(ushort4*)&Ash[(cq + 1) * SPAD + colw] = make_ushort4(r0.y, r1.y, r2.y, r3.y);
            *(ushort4*)&Ash[(cq + 2) * SPAD + colw] = make_ushort4(r0.z, r1.z, r2.z, r3.z);
            *(ushort4*)&Ash[(cq + 3) * SPAD + colw] = make_ushort4(r0.w, r1.w, r2.w, r3.w);
        }
        __syncthreads();
#pragma unroll
        for (int k0 = 0; k0 < 64; k0 += 32) {
            bf16x8 afh[4];
#pragma unroll
            for (int ct = 0; ct < 4; ++ct) {
                int rr = ct * 16 + l16;
                int ro = rr * SPAD + (((k0 + quad * 8) + (((rr >> 2) & 7) << 3)) & 63);
                afh[ct] = *(const bf16x8*)&Ash[ro];
            }
            int go = kt + k0 + quad * 8;
            bf16x8 b0h = *(const bf16x8*)(w0h + go);
            bf16x8 b1h = *(const bf16x8*)(w1h + go);
#pragma unroll
            for (int ct = 0; ct < 4; ++ct) {
                acc[ct][0] = __builtin_amdgcn_mfma_f32_16x16x32_bf16(afh[ct], b0h, acc[ct][0], 0, 0, 0);
                acc[ct][1] = __builtin_amdgcn_mfma_f32_16x16x32_bf16(afh[ct], b1h, acc[ct][1], 0, 0, 0);
            }
        }
    }
    float* xb = xh + (size_t)(b << 6) * 128;
#pragma unroll
    for (int ct = 0; ct < 4; ++ct)
#pragma unroll
        for (int lt = 0; lt < 2; ++lt)
#pragma unroll
            for (int r = 0; r < 4; ++r)
                atomicAdd(xb + (size_t)(ct * 16 + quad * 4 + r) * 128 + l0 + lt * 16 + l16,
                          acc[ct][lt][r]);
}

// ---------------------------------------------------------------------------
// hmix via MFMA.  One block per (b, j):
//   phase 1: T[k][i] = sum_l H[j][k][l] * xh[b][i][l]   (A=Hbf, B=xh-bf16 LDS)
//   phase 2: y[b][o][k] += sum_i WsT[j][o][i] * T[k][i] (atomics over j)
// grid (32, 16) x 256 (4 waves; wave = 32k of the 128k output).
#define XPAD 136
#define TPAD 72
__global__ __launch_bounds__(256) void k_hmix_mfma(
        const float* __restrict__ xh, const u16* __restrict__ Hbf,
        const u16* __restrict__ WsT, float* __restrict__ y, int lay) {
    __shared__ u16 xsb[64 * XPAD];   // [i][l]
    __shared__ u16 Ts[128 * TPAD];   // [k][i]
    int t = threadIdx.x;
    int wave = t >> 6, lane = t & 63, quad = lane >> 4, l16 = lane & 15;
    int b = blockIdx.x, j = blockIdx.y;
    const float* xb = xh + (size_t)b * DIM * MODE;
    for (int idx = t; idx < DIM * MODE; idx += 256)
        xsb[(idx >> 7) * XPAD + (idx & 127)] = to_bf16(xb[idx]);
    __syncthreads();
    int k_base = wave * 32;
    // phase 1
    {
        f32x4 acc[2][4] = {};
        const u16* Hj = Hbf + (size_t)j * MODE * MODE;
#pragma unroll
        for (int l0 = 0; l0 < 128; l0 += 32) {
            bf16x8 af[2], bf[4];
#pragma unroll
            for (int mt = 0; mt < 2; ++mt)
                af[mt] = *(const bf16x8*)(Hj + (size_t)(k_base + mt * 16 + l16) * 128 + l0 + quad * 8);
#pragma unroll
            for (int nt = 0; nt < 4; ++nt)
                bf[nt] = *(const bf16x8*)&xsb[(nt * 16 + l16) * XPAD + l0 + quad * 8];
#pragma unroll
            for (int mt = 0; mt < 2; ++mt)
#pragma unroll
                for (int nt = 0; nt < 4; ++nt)
                    acc[mt][nt] = __builtin_amdgcn_mfma_f32_16x16x32_bf16(af[mt], bf[nt], acc[mt][nt], 0, 0, 0);
        }
#pragma unroll
        for (int mt = 0; mt < 2; ++mt)
#pragma unroll
            for (int nt = 0; nt < 4; ++nt)
#pragma unroll
                for (int r = 0; r < 4; ++r)
                    Ts[(k_base + mt * 16 + quad * 4 + r) * TPAD + nt * 16 + l16] =
                        to_bf16(acc[mt][nt][r]);
    }
    __syncthreads();
    // phase 2
    {
        f32x4 acc[4][2] = {};
        const u16* Wj = WsT + ((size_t)lay * JM + j) * DIM * DIM;
#pragma unroll
        for (int i0 = 0; i0 < 64; i0 += 32) {
            bf16x8 af[4], bf[2];
#pragma unroll
            for (int mt = 0; mt < 4; ++mt)
                af[mt] = *(const bf16x8*)(Wj + (size_t)(mt * 16 + l16) * 64 + i0 + quad * 8);
#pragma unroll
            for (int nt = 0; nt < 2; ++nt)
                bf[nt] = *(const bf16x8*)&Ts[(k_base + nt * 16 + l16) * TPAD + i0 + quad * 8];
#pragma unroll
            for (int mt = 0; mt < 4; ++mt)
#pragma unroll
                for (int nt = 0; nt < 2; ++nt)
                    acc[mt][nt] = __builtin_amdgcn_mfma_f32_16x16x32_bf16(af[mt], bf[nt], acc[mt][nt], 0, 0, 0);
        }
        float* yb = y + (size_t)b * DIM * MODE;
#pragma unroll
        for (int mt = 0; mt < 4; ++mt)
#pragma unroll
            for (int nt = 0; nt < 2; ++nt)
#pragma unroll
                for (int r = 0; r < 4; ++r)
                    atomicAdd(yb + (size_t)(mt * 16 + quad * 4 + r) * 128 + k_base + nt * 16 + l16,
                              acc[mt][nt][r]);
    }
}

// A buffer in FRAG-MAJOR layout (y|Wconv, single bf16 plane).  grid (32) x 256
__global__ __launch_bounds__(256) void k_build_A(
        const float* __restrict__ y, const float* __restrict__ Wconv,
        u16* __restrict__ Ah, int lay) {
    int b = blockIdx.x;
    for (int idx = threadIdx.x; idx < 12288; idx += 256) {
        int i = idx & 7, l16 = (idx >> 3) & 15, quad = (idx >> 7) & 3,
            ot = (idx >> 9) & 3, ks = idx >> 11;
        int o = ot * 16 + l16;
        int k = ks * 32 + quad * 8 + i;
        float v = (k < 128) ? y[((size_t)b * DIM + o) * MODE + k]
                            : Wconv[(size_t)lay * DIM * DIM + o * DIM + (k - 128)];
        Ah[(size_t)b * 12288 + idx] = to_bf16(v);
    }
}

// ---------------------------------------------------------------------------
// inv_conv: h' = act(A(64x192) @ B(192 x 16384x) + bconv), in-place on h.
// Round-2 structure (128-x tile/block, grid 4096, dense stores) with the
// LDS footprint cut 40KB -> 24KB for occupancy:
//   - h-input fragments read DIRECT from global ([x][c] is frag-contiguous;
//     fine at the 128-x per-block footprint, r3 showed regression was the
//     256-x footprint, not the read pattern);
//   - output staging buffer ALIASES Ash (dead after ks-loop; one extra
//     barrier) -> total LDS 24KB, 5 blocks/CU via __launch_bounds__(256,5).
template <bool DO_MLP>
__global__ __launch_bounds__(256, 5) void k_inv_conv_mfma(
        const u16* __restrict__ Afh,
        const u16* __restrict__ Bfh,
        u16* __restrict__ Hh,
        const float* __restrict__ bconv, int lay,
        const u16* __restrict__ W1h,
        const float* __restrict__ b1, const float* __restrict__ W2,
        const float* __restrict__ b2, float* __restrict__ out) {
    __shared__ u16 sh[12288];   // phase 1: A frags (24KB); phase 2: osh (16KB)
    int t = threadIdx.x;
    int wave = t >> 6, lane = t & 63, quad = lane >> 4, l16 = lane & 15;
    // XCD-bijective swizzle: 4096 blocks, 8 XCDs -> each XCD gets contiguous
    // 512-block chunk = all 32 b x 16 xt (2048 consecutive x).
    int bid = blockIdx.x;
    int swz = (bid & 7) * 512 + (bid >> 3);
    int b = swz & 31;
    int x0 = (swz >> 5) * 128;
    int xw = wave * 32;

    // stage A (24KB) once per block
    const u16* afb = Afh + (size_t)b * 12288;
#pragma unroll
    for (int i = 0; i < 6; ++i) {
        int idx = i * 256 + t;
        *(bf16x8*)&sh[idx * 8] = *(const bf16x8*)(afb + (size_t)idx * 8);
    }
    // preload all 12 B fragments: bases plane (ks 0..3) + h direct (ks 4..5)
    bf16x8 bg[4][2], hf[2][2];
#pragma unroll
    for (int ks = 0; ks < 4; ++ks)
#pragma unroll
        for (int x2 = 0; x2 < 2; ++x2) {
            int xl = xw + x2 * 16 + l16;
            bg[ks][x2] = *(const bf16x8*)(Bfh + (size_t)((ks * 4 + quad) * 16384 + x0 + xl) * 8);
        }
#pragma unroll
    for (int ks = 0; ks < 2; ++ks)
#pragma unroll
        for (int x2 = 0; x2 < 2; ++x2) {
            int xl = xw + x2 * 16 + l16;
            hf[ks][x2] = *(const bf16x8*)(Hh + ((size_t)(b << 14) + x0 + xl) * 64
                                          + ks * 32 + quad * 8);
        }
    __syncthreads();   // Ash ready

    f32x4 acc[4][2] = {};
#pragma unroll
    for (int ks = 0; ks < 6; ++ks) {
        bf16x8 afh[4];
#pragma unroll
        for (int ot = 0; ot < 4; ++ot)
            afh[ot] = *(const bf16x8*)&sh[(((ks * 4 + ot) * 4 + quad) * 16 + l16) * 8];
#pragma unroll
        for (int ot = 0; ot < 4; ++ot)
#pragma unroll
            for (int x2 = 0; x2 < 2; ++x2)
                acc[ot][x2] = __builtin_amdgcn_mfma_f32_16x16x32_bf16(
                    afh[ot], ks < 4 ? bg[ks][x2] : hf[ks - 4][x2],
                    acc[ot][x2], 0, 0, 0);
    }
    __syncthreads();   // all Ash reads done -> alias sh as output staging

    // epilogue: bias (+gelu for lay 0/1), pack into sh (wave-private rows)
#pragma unroll
    for (int ot = 0; ot < 4; ++ot) {
        float4 bc = *(const float4*)(bconv + lay * DIM + ot * 16 + quad * 4);
#pragma unroll
        for (int x2 = 0; x2 < 2; ++x2) {
            int xl = xw + x2 * 16 + l16;
            float vr[4] = {acc[ot][x2][0] + bc.x, acc[ot][x2][1] + bc.y,
                           acc[ot][x2][2] + bc.z, acc[ot][x2][3] + bc.w};
            if (!DO_MLP) {
#pragma unroll
                for (int r = 0; r < 4; ++r) vr[r] = gelu_fast(vr[r]);
            }
            ushort4 uh;
            uh.x = to_bf16(vr[0]); uh.y = to_bf16(vr[1]);
            uh.z = to_bf16(vr[2]); uh.w = to_bf16(vr[3]);
            int col = ot * 16 + quad * 4;
            *(ushort4*)&sh[xl * 64 + (col ^ ((xl & 7) << 3))] = uh;
        }
    }

    if (!DO_MLP) {
        __syncthreads();   // cross-wave: dense store covers all rows
#pragma unroll
        for (int it = 0; it < 4; ++it) {
            int idx = it * 256 + t;
            int row = idx >> 3, c8 = (idx & 7) * 8;
            size_t dst = ((size_t)(b << 14) + x0 + row) * 64 + c8;
            *(bf16x8*)(Hh + dst) =
                *(const bf16x8*)&sh[row * 64 + (c8 ^ ((row & 7) << 3))];
        }
        return;
    }

    // ---- fused final MLP (lay 2 only): out = gelu(h'@W1+b1)@W2 + b2 ----
    // each wave reads only its own sh rows -> no barrier needed.
#pragma unroll
    for (int x2 = 0; x2 < 2; ++x2) {
        int xl = xw + x2 * 16 + l16;
        bf16x8 ah[2];
#pragma unroll
        for (int ks = 0; ks < 2; ++ks) {
            int ko = ks * 32 + quad * 8;
            ah[ks] = *(const bf16x8*)&sh[xl * 64 + (ko ^ ((xl & 7) << 3))];
        }
        float vo[4] = {0.f, 0.f, 0.f, 0.f};
#pragma unroll
        for (int ft = 0; ft < 8; ++ft) {
            f32x4 a2 = {};
#pragma unroll
            for (int ks = 0; ks < 2; ++ks) {
                size_t o = (size_t)(ft * 16 + l16) * 64 + ks * 32 + quad * 8;
                bf16x8 bh = *(const bf16x8*)(W1h + o);
                a2 = __builtin_amdgcn_mfma_f32_16x16x32_bf16(ah[ks], bh, a2, 0, 0, 0);
            }
            float bb = b1[ft * 16 + l16];
            float w2 = W2[ft * 16 + l16];
#pragma unroll
            for (int r = 0; r < 4; ++r)
                vo[r] += gelu_fast(a2[r] + bb) * w2;
        }
#pragma unroll
        for (int r = 0; r < 4; ++r) {
            float v = vo[r];
            v += __shfl_xor(v, 1);
            v += __shfl_xor(v, 2);
            v += __shfl_xor(v, 4);
            v += __shfl_xor(v, 8);
            vo[r] = v;
        }
        if (l16 == 0) {
            float bb2 = b2[0];
            float4 o4 = make_float4(vo[0] + bb2, vo[1] + bb2,
                                    vo[2] + bb2, vo[3] + bb2);
            *(float4*)(out + (size_t)b * NXX + x0 + xw + x2 * 16 + quad * 4) = o4;
        }
    }
}

// ---------------------------------------------------------------------------
extern "C" void kernel_launch(void* const* d_in, const int* in_sizes, int n_in,
                              void* d_out, int out_size, void* d_ws, size_t ws_size,
                              hipStream_t stream) {
    const float* x      = (const float*)d_in[0];
    const float* bases  = (const float*)d_in[1];
    const float* wbases = (const float*)d_in[2];
    const float* product= (const float*)d_in[3];
    const float* Dout   = (const float*)d_in[4];
    const float* Din    = (const float*)d_in[5];
    const float* A      = (const float*)d_in[6];
    const float* Bm     = (const float*)d_in[7];
    const float* Wsp    = (const float*)d_in[8];
    const float* Wconv  = (const float*)d_in[9];
    const float* bconv  = (const float*)d_in[10];
    const float* W0     = (const float*)d_in[11];
    const float* b0     = (const float*)d_in[12];
    const float* W1     = (const float*)d_in[13];
    const float* b1     = (const float*)d_in[14];
    const float* W2     = (const float*)d_in[15];
    const float* b2     = (const float*)d_in[16];
    float* out = (float*)d_out;

    const size_t need = 79314944;
    if (ws_size < need) {
        k_zero<<<dim3((out_size + 255) / 256), dim3(256), 0, stream>>>(out, out_size);
        return;
    }

    char* W = (char*)d_ws;
    size_t off = 0;
    auto alloc = [&](size_t bytes) { void* p = W + off; off += bytes; return p; };
    u16*   Hbf      = (u16*)alloc(524288);
    u16*   WsT      = (u16*)alloc(393216);
    u16*   bases_hi = (u16*)alloc(4194304);
    u16*   wbT_hi   = (u16*)alloc(4194304);
    u16*   Abuf_hi  = (u16*)alloc(786432);
    float* ybuf     = (float*)alloc(1048576);
    float* xh       = (float*)alloc(1048576);   // must follow ybuf (joint zeroing)
    u16*   h_hi     = (u16*)alloc(67108864);
    u16*   w1t_hi   = (u16*)alloc(16384);

    k_build_H<<<dim3(1024), dim3(256), 0, stream>>>(Dout, Din, product, A, Bm, Hbf);
    k_setup_wst<<<dim3(768), dim3(256), 0, stream>>>(Wsp, WsT);
    k_setup_bases<<<dim3(8192), dim3(256), 0, stream>>>(bases, bases_hi);
    k_setup_wbT<<<dim3(512, 4), dim3(256), 0, stream>>>(wbases, wbT_hi);
    k_setup_w1t<<<dim3(32), dim3(256), 0, stream>>>(W1, w1t_hi);
    k_fc0<<<dim3(512, B_SZ), dim3(256), 0, stream>>>(x, W0, b0, h_hi);

    for (int lay = 0; lay < N_LAY; ++lay) {
        int last = (lay == N_LAY - 1);
        k_zero<<<dim3(2048), dim3(256), 0, stream>>>(ybuf, 524288);  // ybuf + xh
        k_spectral_mfma<<<dim3(B_SZ, 32), dim3(256), 0, stream>>>(
            h_hi, wbT_hi, xh);
        k_hmix_mfma<<<dim3(B_SZ, JM), dim3(256), 0, stream>>>(
            xh, Hbf, WsT, ybuf, lay);
        k_build_A<<<dim3(B_SZ), dim3(256), 0, stream>>>(ybuf, Wconv, Abuf_hi, lay);
        dim3 g(4096), blk(256);
        if (last)
            k_inv_conv_mfma<true><<<g, blk, 0, stream>>>(
                Abuf_hi, bases_hi, h_hi, bconv, lay,
                w1t_hi, b1, W2, b2, out);
        else
            k_inv_conv_mfma<false><<<g, blk, 0, stream>>>(
                Abuf_hi, bases_hi, h_hi, bconv, lay,
                w1t_hi, b1, W2, b2, out);
    }
}

// Round 5
// 460.861 us; speedup vs baseline: 1.1010x; 1.0245x over previous
//
#include <hip/hip_runtime.h>
#include <hip/hip_bf16.h>
#include <math.h>

#define B_SZ   32
#define NXX    16384
#define IN_DIM 3
#define DIM    64
#define JM     16
#define MODE   128
#define RANKK  4
#define FC_DIM 128
#define N_LAY  3

typedef __attribute__((ext_vector_type(8))) short bf16x8;
typedef __attribute__((ext_vector_type(4))) float f32x4;
typedef unsigned short u16;

// Fast gelu: v * sigmoid(2u), u = sqrt(2/pi)*(v + 0.044715 v^3).
__device__ __forceinline__ float gelu_fast(float v) {
    float p = v * (0.7978845608f + 0.0356774081f * v * v);
    float e = __expf(-2.f * p);
    return v * __builtin_amdgcn_rcpf(1.f + e);
}
__device__ __forceinline__ u16 to_bf16(float v) {
    __hip_bfloat16 b = __float2bfloat16(v);
    return *(u16*)&b;
}

// ---------------------------------------------------------------------------
__global__ __launch_bounds__(256) void k_zero(float* __restrict__ p, int n) {
    int i = blockIdx.x * 256 + threadIdx.x;
    if (i < n) p[i] = 0.f;
}

// H[j,k,l] bf16 row-major (l contig = A-frag-ready for m=k, kk=l).
__global__ __launch_bounds__(256) void k_build_H(
        const float* __restrict__ Dout, const float* __restrict__ Din,
        const float* __restrict__ product, const float* __restrict__ A,
        const float* __restrict__ Bm, u16* __restrict__ Hbf) {
    int idx = blockIdx.x * 256 + threadIdx.x;
    int j = idx >> 14;
    int k = (idx >> 7) & 127;
    int l = idx & 127;
    float v = Dout[j * MODE + k] * Din[j * MODE + l] * product[k * MODE + l];
#pragma unroll
    for (int r = 0; r < RANKK; ++r)
        v += A[(j * RANKK + r) * MODE + k] * Bm[(j * RANKK + r) * MODE + l];
    Hbf[idx] = to_bf16(v);
}

// WsT[lay][j][o][i] = Wsp[lay][i][o][j] bf16 (i contig).  grid 768 x 256.
__global__ __launch_bounds__(256) void k_setup_wst(
        const float* __restrict__ Wsp, u16* __restrict__ WsT) {
    int idx = blockIdx.x * 256 + threadIdx.x;   // ((lay*16+j)*64+o)*64+i
    int i = idx & 63, o = (idx >> 6) & 63, j = (idx >> 12) & 15, lay = idx >> 16;
    WsT[idx] = to_bf16(Wsp[(((size_t)lay * 64 + i) * 64 + o) * 16 + j]);
}

// bases (fp32 [x][k]) -> FRAG-MAJOR single bf16 plane.  grid 8192 x 256.
__global__ __launch_bounds__(256) void k_setup_bases(
        const float* __restrict__ bases, u16* __restrict__ bh) {
    int idx = blockIdx.x * 256 + threadIdx.x;
    int x = idx >> 7, k = idx & 127;
    size_t off = (size_t)(k >> 3) * 131072 + (size_t)x * 8 + (k & 7);
    bh[off] = to_bf16(bases[idx]);
}

// wbT[l][x] = wbases[x][l], single bf16 plane.  grid (512, 4) x 256, LDS-tiled.
__global__ __launch_bounds__(256) void k_setup_wbT(
        const float* __restrict__ wb, u16* __restrict__ Th) {
    __shared__ float tile[32][33];
    int bx = blockIdx.x, bl = blockIdx.y;
    int t = threadIdx.x;
    int i = t >> 5, jj = t & 31;
#pragma unroll
    for (int r = 0; r < 4; ++r)
        tile[i + r * 8][jj] = wb[(size_t)(bx * 32 + i + r * 8) * MODE + bl * 32 + jj];
    __syncthreads();
#pragma unroll
    for (int r = 0; r < 4; ++r) {
        int l = bl * 32 + i + r * 8;
        int x = bx * 32 + jj;
        Th[(size_t)l * NXX + x] = to_bf16(tile[jj][i + r * 8]);
    }
}

// W1T[f*64+c] = W1[c*128+f] single bf16 plane.  grid 32 x 256
__global__ __launch_bounds__(256) void k_setup_w1t(
        const float* __restrict__ W1, u16* __restrict__ wh) {
    int i = blockIdx.x * 256 + threadIdx.x;
    int f = i >> 6, c = i & 63;
    wh[i] = to_bf16(W1[c * FC_DIM + f]);
}

// fc0: h[b,x,c] (single bf16 plane), coalesced ushort8 stores.
// grid (512, 32) x 256.
__global__ __launch_bounds__(256) void k_fc0(
        const float* __restrict__ x, const float* __restrict__ W0,
        const float* __restrict__ b0, u16* __restrict__ hh) {
    __shared__ float w0s[IN_DIM * DIM + DIM];
    int t = threadIdx.x;
    if (t < IN_DIM * DIM) w0s[t] = W0[t];
    if (t < DIM) w0s[IN_DIM * DIM + t] = b0[t];
    __syncthreads();
    int b = blockIdx.y;
    int xi = blockIdx.x * 32 + (t >> 3);
    int c8 = (t & 7) * 8;
    const float* xp = x + ((size_t)b * NXX + xi) * IN_DIM;
    float x0 = xp[0], x1 = xp[1], x2 = xp[2];
    u16 rh[8];
#pragma unroll
    for (int i = 0; i < 8; ++i) {
        int c = c8 + i;
        float v = x0 * w0s[c] + x1 * w0s[DIM + c] + x2 * w0s[2 * DIM + c]
                + w0s[3 * DIM + c];
        rh[i] = to_bf16(v);
    }
    size_t o = ((size_t)(b << 14) + xi) * 64 + c8;
    *(ushort4*)(hh + o)     = make_ushort4(rh[0], rh[1], rh[2], rh[3]);
    *(ushort4*)(hh + o + 4) = make_ushort4(rh[4], rh[5], rh[6], rh[7]);
}

// ---------------------------------------------------------------------------
// Spectral via MFMA: xh[b][c][l] += sum_x h[b][x][c] * wbases[x][l]
// grid (32 b, 32 ks) x 256 (4 waves; wave = 16c x 32l), 512-x slab per block.
// r5: register prefetch of next 64-x staging slab (latency hides under MFMA)
// + XCD swizzle (each XCD owns 4 contiguous slabs x all b -> wbT L2-resident).
#define SPAD 72
__global__ __launch_bounds__(256) void k_spectral_mfma(
        const u16* __restrict__ Hh,
        const u16* __restrict__ Wh,
        float* __restrict__ xh) {
    __shared__ u16 Ash[64 * SPAD];
    int t = threadIdx.x;
    int wave = t >> 6, lane = t & 63, quad = lane >> 4, l16 = lane & 15;
    int lin = blockIdx.y * 32 + blockIdx.x;
    int swz = (lin & 7) * 128 + (lin >> 3);
    int b = swz & 31;
    int x0 = (swz >> 5) * 512;
    int cq = (t & 15) * 4;
    int xq = (t >> 4) * 4;
    int colw = (xq + ((t & 7) << 3)) & 63;
    const u16* srch = Hh + ((size_t)(b << 14) + x0 + xq) * 64 + cq;
    int l0 = wave * 32;
    const u16* w0h = Wh + (size_t)(l0 + l16) * NXX + x0;
    const u16* w1h = Wh + (size_t)(l0 + 16 + l16) * NXX + x0;
    ushort4 r0, r1, r2, r3;
    {
        const u16* s = srch;
        r0 = *(const ushort4*)(s);
        r1 = *(const ushort4*)(s + 64);
        r2 = *(const ushort4*)(s + 128);
        r3 = *(const ushort4*)(s + 192);
    }
    f32x4 acc[4][2] = {};
    for (int kt = 0; kt < 512; kt += 64) {
        __syncthreads();
        *(ushort4*)&Ash[(cq + 0) * SPAD + colw] = make_ushort4(r0.x, r1.x, r2.x, r3.x);
        *(ushort4*)&Ash[(cq + 1) * SPAD + colw] = make_ushort4(r0.y, r1.y, r2.y, r3.y);
        *(ushort4*)&Ash[(cq + 2) * SPAD + colw] = make_ushort4(r0.z, r1.z, r2.z, r3.z);
        *(ushort4*)&Ash[(cq + 3) * SPAD + colw] = make_ushort4(r0.w, r1.w, r2.w, r3.w);
        if (kt + 64 < 512) {   // prefetch next slab; completes during MFMA
            const u16* s = srch + (size_t)(kt + 64) * 64;
            r0 = *(const ushort4*)(s);
            r1 = *(const ushort4*)(s + 64);
            r2 = *(const ushort4*)(s + 128);
            r3 = *(const ushort4*)(s + 192);
        }
        __builtin_amdgcn_sched_barrier(0);
        __syncthreads();
#pragma unroll
        for (int k0 = 0; k0 < 64; k0 += 32) {
            bf16x8 afh[4];
#pragma unroll
            for (int ct = 0; ct < 4; ++ct) {
                int rr = ct * 16 + l16;
                int ro = rr * SPAD + (((k0 + quad * 8) + (((rr >> 2) & 7) << 3)) & 63);
                afh[ct] = *(const bf16x8*)&Ash[ro];
            }
            int go = kt + k0 + quad * 8;
            bf16x8 b0h = *(const bf16x8*)(w0h + go);
            bf16x8 b1h = *(const bf16x8*)(w1h + go);
#pragma unroll
            for (int ct = 0; ct < 4; ++ct) {
                acc[ct][0] = __builtin_amdgcn_mfma_f32_16x16x32_bf16(afh[ct], b0h, acc[ct][0], 0, 0, 0);
                acc[ct][1] = __builtin_amdgcn_mfma_f32_16x16x32_bf16(afh[ct], b1h, acc[ct][1], 0, 0, 0);
            }
        }
    }
    float* xb = xh + (size_t)(b << 6) * 128;
#pragma unroll
    for (int ct = 0; ct < 4; ++ct)
#pragma unroll
        for (int lt = 0; lt < 2; ++lt)
#pragma unroll
            for (int r = 0; r < 4; ++r)
                atomicAdd(xb + (size_t)(ct * 16 + quad * 4 + r) * 128 + l0 + lt * 16 + l16,
                          acc[ct][lt][r]);
}

// ---------------------------------------------------------------------------
// hmix via MFMA.  One block per (b, j):
//   phase 1: T[k][i] = sum_l H[j][k][l] * xh[b][i][l]   (A=Hbf, B=xh-bf16 LDS)
//   phase 2: y[b][o][k] += sum_i WsT[j][o][i] * T[k][i] (atomics over j)
// grid (32, 16) x 256 (4 waves; wave = 32k of the 128k output).
#define XPAD 136
#define TPAD 72
__global__ __launch_bounds__(256) void k_hmix_mfma(
        const float* __restrict__ xh, const u16* __restrict__ Hbf,
        const u16* __restrict__ WsT, float* __restrict__ y, int lay) {
    __shared__ u16 xsb[64 * XPAD];   // [i][l]
    __shared__ u16 Ts[128 * TPAD];   // [k][i]
    int t = threadIdx.x;
    int wave = t >> 6, lane = t & 63, quad = lane >> 4, l16 = lane & 15;
    int b = blockIdx.x, j = blockIdx.y;
    const float* xb = xh + (size_t)b * DIM * MODE;
    for (int idx = t; idx < DIM * MODE; idx += 256)
        xsb[(idx >> 7) * XPAD + (idx & 127)] = to_bf16(xb[idx]);
    __syncthreads();
    int k_base = wave * 32;
    // phase 1
    {
        f32x4 acc[2][4] = {};
        const u16* Hj = Hbf + (size_t)j * MODE * MODE;
#pragma unroll
        for (int l0 = 0; l0 < 128; l0 += 32) {
            bf16x8 af[2], bf[4];
#pragma unroll
            for (int mt = 0; mt < 2; ++mt)
                af[mt] = *(const bf16x8*)(Hj + (size_t)(k_base + mt * 16 + l16) * 128 + l0 + quad * 8);
#pragma unroll
            for (int nt = 0; nt < 4; ++nt)
                bf[nt] = *(const bf16x8*)&xsb[(nt * 16 + l16) * XPAD + l0 + quad * 8];
#pragma unroll
            for (int mt = 0; mt < 2; ++mt)
#pragma unroll
                for (int nt = 0; nt < 4; ++nt)
                    acc[mt][nt] = __builtin_amdgcn_mfma_f32_16x16x32_bf16(af[mt], bf[nt], acc[mt][nt], 0, 0, 0);
        }
#pragma unroll
        for (int mt = 0; mt < 2; ++mt)
#pragma unroll
            for (int nt = 0; nt < 4; ++nt)
#pragma unroll
                for (int r = 0; r < 4; ++r)
                    Ts[(k_base + mt * 16 + quad * 4 + r) * TPAD + nt * 16 + l16] =
                        to_bf16(acc[mt][nt][r]);
    }
    __syncthreads();
    // phase 2
    {
        f32x4 acc[4][2] = {};
        const u16* Wj = WsT + ((size_t)lay * JM + j) * DIM * DIM;
#pragma unroll
        for (int i0 = 0; i0 < 64; i0 += 32) {
            bf16x8 af[4], bf[2];
#pragma unroll
            for (int mt = 0; mt < 4; ++mt)
                af[mt] = *(const bf16x8*)(Wj + (size_t)(mt * 16 + l16) * 64 + i0 + quad * 8);
#pragma unroll
            for (int nt = 0; nt < 2; ++nt)
                bf[nt] = *(const bf16x8*)&Ts[(k_base + nt * 16 + l16) * TPAD + i0 + quad * 8];
#pragma unroll
            for (int mt = 0; mt < 4; ++mt)
#pragma unroll
                for (int nt = 0; nt < 2; ++nt)
                    acc[mt][nt] = __builtin_amdgcn_mfma_f32_16x16x32_bf16(af[mt], bf[nt], acc[mt][nt], 0, 0, 0);
        }
        float* yb = y + (size_t)b * DIM * MODE;
#pragma unroll
        for (int mt = 0; mt < 4; ++mt)
#pragma unroll
            for (int nt = 0; nt < 2; ++nt)
#pragma unroll
                for (int r = 0; r < 4; ++r)
                    atomicAdd(yb + (size_t)(mt * 16 + quad * 4 + r) * 128 + k_base + nt * 16 + l16,
                              acc[mt][nt][r]);
    }
}

// A buffer in FRAG-MAJOR layout (y|Wconv, single bf16 plane).  grid (32) x 256
__global__ __launch_bounds__(256) void k_build_A(
        const float* __restrict__ y, const float* __restrict__ Wconv,
        u16* __restrict__ Ah, int lay) {
    int b = blockIdx.x;
    for (int idx = threadIdx.x; idx < 12288; idx += 256) {
        int i = idx & 7, l16 = (idx >> 3) & 15, quad = (idx >> 7) & 3,
            ot = (idx >> 9) & 3, ks = idx >> 11;
        int o = ot * 16 + l16;
        int k = ks * 32 + quad * 8 + i;
        float v = (k < 128) ? y[((size_t)b * DIM + o) * MODE + k]
                            : Wconv[(size_t)lay * DIM * DIM + o * DIM + (k - 128)];
        Ah[(size_t)b * 12288 + idx] = to_bf16(v);
    }
}

// ---------------------------------------------------------------------------
// inv_conv: h' = act(A(64x192) @ B(192 x 16384x) + bconv), in-place on h.
// r5: force memory-level parallelism — A loaded to regs FIRST (oldest in
// vmcnt queue), then all 12 B frags, then sched_barrier(0) so the compiler
// cannot sink/serialize the loads (r0-r4 all had VGPR<=64 = serialized
// loads).  __launch_bounds__(256,4) -> VGPR cap 128.  LDS 24KB (output
// staging aliases Ash after the ks-loop).
template <bool DO_MLP>
__global__ __launch_bounds__(256, 4) void k_inv_conv_mfma(
        const u16* __restrict__ Afh,
        const u16* __restrict__ Bfh,
        u16* __restrict__ Hh,
        const float* __restrict__ bconv, int lay,
        const u16* __restrict__ W1h,
        const float* __restrict__ b1, const float* __restrict__ W2,
        const float* __restrict__ b2, float* __restrict__ out) {
    __shared__ u16 sh[12288];   // phase 1: A frags (24KB); phase 2: osh (16KB)
    int t = threadIdx.x;
    int wave = t >> 6, lane = t & 63, quad = lane >> 4, l16 = lane & 15;
    // XCD-bijective swizzle: 4096 blocks, 8 XCDs -> each XCD gets contiguous
    // 512-block chunk = all 32 b x 16 xt (2048 consecutive x).
    int bid = blockIdx.x;
    int swz = (bid & 7) * 512 + (bid >> 3);
    int b = swz & 31;
    int x0 = (swz >> 5) * 128;
    int xw = wave * 32;

    // issue ALL loads up front: A first, then B (bases, h)
    const u16* afb = Afh + (size_t)b * 12288;
    bf16x8 areg[6];
#pragma unroll
    for (int i = 0; i < 6; ++i)
        areg[i] = *(const bf16x8*)(afb + (size_t)(i * 256 + t) * 8);
    bf16x8 bg[4][2], hf[2][2];
#pragma unroll
    for (int ks = 0; ks < 4; ++ks)
#pragma unroll
        for (int x2 = 0; x2 < 2; ++x2) {
            int xl = xw + x2 * 16 + l16;
            bg[ks][x2] = *(const bf16x8*)(Bfh + (size_t)((ks * 4 + quad) * 16384 + x0 + xl) * 8);
        }
#pragma unroll
    for (int ks = 0; ks < 2; ++ks)
#pragma unroll
        for (int x2 = 0; x2 < 2; ++x2) {
            int xl = xw + x2 * 16 + l16;
            hf[ks][x2] = *(const bf16x8*)(Hh + ((size_t)(b << 14) + x0 + xl) * 64
                                          + ks * 32 + quad * 8);
        }
    __builtin_amdgcn_sched_barrier(0);
    // A regs -> LDS (waits only on the 6 A loads; B still in flight)
#pragma unroll
    for (int i = 0; i < 6; ++i)
        *(bf16x8*)&sh[(i * 256 + t) * 8] = areg[i];
    __syncthreads();   // Ash ready

    f32x4 acc[4][2] = {};
#pragma unroll
    for (int ks = 0; ks < 6; ++ks) {
        bf16x8 afh[4];
#pragma unroll
        for (int ot = 0; ot < 4; ++ot)
            afh[ot] = *(const bf16x8*)&sh[(((ks * 4 + ot) * 4 + quad) * 16 + l16) * 8];
#pragma unroll
        for (int ot = 0; ot < 4; ++ot)
#pragma unroll
            for (int x2 = 0; x2 < 2; ++x2)
                acc[ot][x2] = __builtin_amdgcn_mfma_f32_16x16x32_bf16(
                    afh[ot], ks < 4 ? bg[ks][x2] : hf[ks - 4][x2],
                    acc[ot][x2], 0, 0, 0);
    }
    __syncthreads();   // all Ash reads done -> alias sh as output staging

    // epilogue: bias (+gelu for lay 0/1), pack into sh (wave-private rows)
#pragma unroll
    for (int ot = 0; ot < 4; ++ot) {
        float4 bc = *(const float4*)(bconv + lay * DIM + ot * 16 + quad * 4);
#pragma unroll
        for (int x2 = 0; x2 < 2; ++x2) {
            int xl = xw + x2 * 16 + l16;
            float vr[4] = {acc[ot][x2][0] + bc.x, acc[ot][x2][1] + bc.y,
                           acc[ot][x2][2] + bc.z, acc[ot][x2][3] + bc.w};
            if (!DO_MLP) {
#pragma unroll
                for (int r = 0; r < 4; ++r) vr[r] = gelu_fast(vr[r]);
            }
            ushort4 uh;
            uh.x = to_bf16(vr[0]); uh.y = to_bf16(vr[1]);
            uh.z = to_bf16(vr[2]); uh.w = to_bf16(vr[3]);
            int col = ot * 16 + quad * 4;
            *(ushort4*)&sh[xl * 64 + (col ^ ((xl & 7) << 3))] = uh;
        }
    }

    if (!DO_MLP) {
        __syncthreads();   // cross-wave: dense store covers all rows
#pragma unroll
        for (int it = 0; it < 4; ++it) {
            int idx = it * 256 + t;
            int row = idx >> 3, c8 = (idx & 7) * 8;
            size_t dst = ((size_t)(b << 14) + x0 + row) * 64 + c8;
            *(bf16x8*)(Hh + dst) =
                *(const bf16x8*)&sh[row * 64 + (c8 ^ ((row & 7) << 3))];
        }
        return;
    }

    // ---- fused final MLP (lay 2 only): out = gelu(h'@W1+b1)@W2 + b2 ----
    // each wave reads only its own sh rows -> no barrier needed.
#pragma unroll
    for (int x2 = 0; x2 < 2; ++x2) {
        int xl = xw + x2 * 16 + l16;
        bf16x8 ah[2];
#pragma unroll
        for (int ks = 0; ks < 2; ++ks) {
            int ko = ks * 32 + quad * 8;
            ah[ks] = *(const bf16x8*)&sh[xl * 64 + (ko ^ ((xl & 7) << 3))];
        }
        float vo[4] = {0.f, 0.f, 0.f, 0.f};
#pragma unroll
        for (int ft = 0; ft < 8; ++ft) {
            f32x4 a2 = {};
#pragma unroll
            for (int ks = 0; ks < 2; ++ks) {
                size_t o = (size_t)(ft * 16 + l16) * 64 + ks * 32 + quad * 8;
                bf16x8 bh = *(const bf16x8*)(W1h + o);
                a2 = __builtin_amdgcn_mfma_f32_16x16x32_bf16(ah[ks], bh, a2, 0, 0, 0);
            }
            float bb = b1[ft * 16 + l16];
            float w2 = W2[ft * 16 + l16];
#pragma unroll
            for (int r = 0; r < 4; ++r)
                vo[r] += gelu_fast(a2[r] + bb) * w2;
        }
#pragma unroll
        for (int r = 0; r < 4; ++r) {
            float v = vo[r];
            v += __shfl_xor(v, 1);
            v += __shfl_xor(v, 2);
            v += __shfl_xor(v, 4);
            v += __shfl_xor(v, 8);
            vo[r] = v;
        }
        if (l16 == 0) {
            float bb2 = b2[0];
            float4 o4 = make_float4(vo[0] + bb2, vo[1] + bb2,
                                    vo[2] + bb2, vo[3] + bb2);
            *(float4*)(out + (size_t)b * NXX + x0 + xw + x2 * 16 + quad * 4) = o4;
        }
    }
}

// ---------------------------------------------------------------------------
extern "C" void kernel_launch(void* const* d_in, const int* in_sizes, int n_in,
                              void* d_out, int out_size, void* d_ws, size_t ws_size,
                              hipStream_t stream) {
    const float* x      = (const float*)d_in[0];
    const float* bases  = (const float*)d_in[1];
    const float* wbases = (const float*)d_in[2];
    const float* product= (const float*)d_in[3];
    const float* Dout   = (const float*)d_in[4];
    const float* Din    = (const float*)d_in[5];
    const float* A      = (const float*)d_in[6];
    const float* Bm     = (const float*)d_in[7];
    const float* Wsp    = (const float*)d_in[8];
    const float* Wconv  = (const float*)d_in[9];
    const float* bconv  = (const float*)d_in[10];
    const float* W0     = (const float*)d_in[11];
    const float* b0     = (const float*)d_in[12];
    const float* W1     = (const float*)d_in[13];
    const float* b1     = (const float*)d_in[14];
    const float* W2     = (const float*)d_in[15];
    const float* b2     = (const float*)d_in[16];
    float* out = (float*)d_out;

    const size_t need = 79314944;
    if (ws_size < need) {
        k_zero<<<dim3((out_size + 255) / 256), dim3(256), 0, stream>>>(out, out_size);
        return;
    }

    char* W = (char*)d_ws;
    size_t off = 0;
    auto alloc = [&](size_t bytes) { void* p = W + off; off += bytes; return p; };
    u16*   Hbf      = (u16*)alloc(524288);
    u16*   WsT      = (u16*)alloc(393216);
    u16*   bases_hi = (u16*)alloc(4194304);
    u16*   wbT_hi   = (u16*)alloc(4194304);
    u16*   Abuf_hi  = (u16*)alloc(786432);
    float* ybuf     = (float*)alloc(1048576);
    float* xh       = (float*)alloc(1048576);   // must follow ybuf (joint zeroing)
    u16*   h_hi     = (u16*)alloc(67108864);
    u16*   w1t_hi   = (u16*)alloc(16384);

    k_build_H<<<dim3(1024), dim3(256), 0, stream>>>(Dout, Din, product, A, Bm, Hbf);
    k_setup_wst<<<dim3(768), dim3(256), 0, stream>>>(Wsp, WsT);
    k_setup_bases<<<dim3(8192), dim3(256), 0, stream>>>(bases, bases_hi);
    k_setup_wbT<<<dim3(512, 4), dim3(256), 0, stream>>>(wbases, wbT_hi);
    k_setup_w1t<<<dim3(32), dim3(256), 0, stream>>>(W1, w1t_hi);
    k_fc0<<<dim3(512, B_SZ), dim3(256), 0, stream>>>(x, W0, b0, h_hi);

    for (int lay = 0; lay < N_LAY; ++lay) {
        int last = (lay == N_LAY - 1);
        k_zero<<<dim3(2048), dim3(256), 0, stream>>>(ybuf, 524288);  // ybuf + xh
        k_spectral_mfma<<<dim3(B_SZ, 32), dim3(256), 0, stream>>>(
            h_hi, wbT_hi, xh);
        k_hmix_mfma<<<dim3(B_SZ, JM), dim3(256), 0, stream>>>(
            xh, Hbf, WsT, ybuf, lay);
        k_build_A<<<dim3(B_SZ), dim3(256), 0, stream>>>(ybuf, Wconv, Abuf_hi, lay);
        dim3 g(4096), blk(256);
        if (last)
            k_inv_conv_mfma<true><<<g, blk, 0, stream>>>(
                Abuf_hi, bases_hi, h_hi, bconv, lay,
                w1t_hi, b1, W2, b2, out);
        else
            k_inv_conv_mfma<false><<<g, blk, 0, stream>>>(
                Abuf_hi, bases_hi, h_hi, bconv, lay,
                w1t_hi, b1, W2, b2, out);
    }
}